// Round 1
// 87.463 us; speedup vs baseline: 1.0261x; 1.0261x over previous
//
#include <hip/hip_runtime.h>
#include <math.h>

#define MX 64
#define NC 4
#define NI 66          // MX + 2
#define NINT 62        // interior tridiagonal unknowns (c2..c63)

typedef _Float16 half4  __attribute__((ext_vector_type(4)));
typedef _Float16 half2v __attribute__((ext_vector_type(2)));

// ---------------------------------------------------------------------------
// Compile-time Thomas constants for the (1/6, 2/3, 1/6) tridiagonal system.
// ---------------------------------------------------------------------------
struct TC { float m[NINT]; float inv[NINT]; };
constexpr TC make_tc() {
    TC tc{};
    double dp = 2.0/3.0;
    tc.m[0] = 0.0f;
    tc.inv[0] = (float)(1.0/dp);
    for (int j = 1; j < NINT; ++j) {
        double m = (1.0/6.0) / dp;
        tc.m[j] = (float)m;
        dp = 2.0/3.0 - m*(1.0/6.0);
        tc.inv[j] = (float)(1.0/dp);
    }
    return tc;
}
__constant__ constexpr TC g_tc = make_tc();

// ---------------------------------------------------------------------------
// Fused coefficient solver: one block, 256 threads.
// R5 change: PREFETCH-THEN-ELIMINATE. The old code consumed one fresh load
// per forward-elimination step; with 1 block resident there are no other
// waves to hide that latency, so any un-hoisted load serializes ~L2-latency
// into the 62-step chain. Now all RHS values land in registers (in-place
// array, identical FP op order) before the recurrence starts.
// ---------------------------------------------------------------------------
__global__ __launch_bounds__(256) void solve_fused(const float* __restrict__ data,
                                                   float4* __restrict__ coefsOut)
{
    __shared__ float cxS[NC][NI][65];   // 68,640 B
    __shared__ half4 chS[NI*NI];        // 34,848 B
    const int t = threadIdx.x;
    const float a = 1.0f/6.0f;

    // ---- Phase A: x-pass, one line per thread: t = (c, y) ----
    {
        const int c = t >> 6, y = t & 63;
        const float* g = data + c*(MX*MX) + y;
        float w[NINT];
        // prefetch ALL loads first (decoupled from the serial chain)
        const float d0 = g[0];
        #pragma unroll
        for (int j = 0; j < NINT; ++j) w[j] = g[(j+1)*MX];
        const float dM = g[63*MX];
        w[0]      -= a*d0;
        w[NINT-1] -= a*dM;
        // pure-register forward elimination (same op order as before)
        #pragma unroll
        for (int j = 1; j < NINT; ++j) w[j] -= g_tc.m[j]*w[j-1];
        float x = w[NINT-1] * g_tc.inv[NINT-1];
        const float c63 = x;
        cxS[c][63][y] = x;
        #pragma unroll
        for (int j = NINT-2; j >= 0; --j) {
            x = (w[j] - a*x) * g_tc.inv[j];
            cxS[c][j+2][y] = x;
        }
        cxS[c][0][y]  = 2.0f*d0 - x;
        cxS[c][1][y]  = d0;
        cxS[c][64][y] = dM;
        cxS[c][65][y] = 2.0f*dM - c63;
    }
    __syncthreads();

    // ---- Phase B: y-pass, 264 lines over 256 threads; results -> chS ----
    for (int line = t; line < NC*NI; line += 256) {
        const int c = line / NI;
        const int i = line - c*NI;
        const float* g = &cxS[c][i][0];
        _Float16* o = ((_Float16*)&chS[i*NI]) + c;

        float w[NINT];
        const float d0 = g[0];
        #pragma unroll
        for (int j = 0; j < NINT; ++j) w[j] = g[j+1];
        const float dM = g[63];
        w[0]      -= a*d0;
        w[NINT-1] -= a*dM;
        #pragma unroll
        for (int j = 1; j < NINT; ++j) w[j] -= g_tc.m[j]*w[j-1];
        float x = w[NINT-1] * g_tc.inv[NINT-1];
        const float c63 = x;
        o[63*NC] = (_Float16)x;
        #pragma unroll
        for (int j = NINT-2; j >= 0; --j) {
            x = (w[j] - a*x) * g_tc.inv[j];
            o[(j+2)*NC] = (_Float16)x;
        }
        o[0*NC]  = (_Float16)(2.0f*d0 - x);
        o[1*NC]  = (_Float16)d0;
        o[64*NC] = (_Float16)dM;
        o[65*NC] = (_Float16)(2.0f*dM - c63);
    }
    __syncthreads();

    const float4* src = (const float4*)chS;
    for (int s = t; s < (NI*NI)/2; s += 256) coefsOut[s] = src[s];
}

// ---------------------------------------------------------------------------
// Interpolation. Per point: packed-fp16 basis (both axes in one Horner
// chain), 16 LDS half4 gathers, 40 pk_fma dot ops. R5 trims: lower clamp
// dropped (inputs are uniform [0,1): trunc of a non-negative float is
// already >= 0; upper min(.,62) kept for the u==1.0 edge), float4-vectorized
// table preload.
// ---------------------------------------------------------------------------
__device__ __forceinline__ float4 eval_pt(const half4* __restrict__ lds,
                                          float ux, float uy)
{
    const float unx = ux * 63.0f;
    const float uny = uy * 63.0f;

    // i = min(trunc(un), 62); t = un - i   (== reference _axis_index for u in [0,1])
    int ix = (int)unx; ix = ix > 62 ? 62 : ix;
    int iy = (int)uny; iy = iy > 62 ? 62 : iy;
    const float tx = unx - (float)ix;
    const float ty = uny - (float)iy;

    // packed (tx,ty) basis, coefficients pre-divided by 6:
    // b0 = ((-1/6 t + 1/2) t - 1/2) t + 1/6
    // b1 = (( 1/2 t - 1  ) t      ) t + 2/3
    // b2 = ((-1/2 t + 1/2) t + 1/2) t + 1/6
    // b3 = 1/6 t^3
    const half2v t = __builtin_bit_cast(half2v, __builtin_amdgcn_cvt_pkrtz(tx, ty));
    const half2v c16  = half2v{(_Float16)(1.0f/6.0f), (_Float16)(1.0f/6.0f)};
    const half2v ch   = half2v{(_Float16)0.5f,  (_Float16)0.5f};
    const half2v cnh  = half2v{(_Float16)-0.5f, (_Float16)-0.5f};
    const half2v cn16 = half2v{(_Float16)(-1.0f/6.0f), (_Float16)(-1.0f/6.0f)};
    const half2v cn1  = half2v{(_Float16)-1.0f, (_Float16)-1.0f};
    const half2v c23  = half2v{(_Float16)(2.0f/3.0f), (_Float16)(2.0f/3.0f)};

    const half2v t2 = t*t;
    half2v b0 = (cn16*t + ch)*t;  b0 = (b0 + cnh)*t + c16;   // (bx0, by0)
    half2v b1 = (ch*t + cn1)*t2 + c23;                        // (bx1, by1)
    half2v b2 = (cnh*t + ch)*t;   b2 = (b2 + ch)*t + c16;     // (bx2, by2)
    half2v b3 = c16*(t*t2);                                   // (bx3, by3)

    // broadcast halves (op_sel-foldable)
    const half2v by0 = __builtin_shufflevector(b0, b0, 1, 1);
    const half2v by1 = __builtin_shufflevector(b1, b1, 1, 1);
    const half2v by2 = __builtin_shufflevector(b2, b2, 1, 1);
    const half2v by3 = __builtin_shufflevector(b3, b3, 1, 1);
    const half2v bx[4] = {
        __builtin_shufflevector(b0, b0, 0, 0),
        __builtin_shufflevector(b1, b1, 0, 0),
        __builtin_shufflevector(b2, b2, 0, 0),
        __builtin_shufflevector(b3, b3, 0, 0),
    };

    const half4* r = lds + (ix*NI + iy);
    half2v t01, t23;
    #pragma unroll
    for (int ar = 0; ar < 4; ++ar) {
        const half4 c0 = r[ar*NI + 0];
        const half4 c1 = r[ar*NI + 1];
        const half4 c2 = r[ar*NI + 2];
        const half4 c3 = r[ar*NI + 3];
        half2v a01 = c0.lo*by0 + c1.lo*by1 + c2.lo*by2 + c3.lo*by3;
        half2v a23 = c0.hi*by0 + c1.hi*by1 + c2.hi*by2 + c3.hi*by3;
        if (ar == 0) { t01 = a01*bx[0];        t23 = a23*bx[0]; }
        else         { t01 = a01*bx[ar] + t01; t23 = a23*bx[ar] + t23; }
    }
    return make_float4((float)t01.x, (float)t01.y, (float)t23.x, (float)t23.y);
}

__global__ __launch_bounds__(512) void interp(const float4* __restrict__ u2,
                                              const float4* __restrict__ coefs4,
                                              float4* __restrict__ out, int NB)
{
    __shared__ half4 lds[NI*NI];
    // float4-vectorized preload: 2178 16-B chunks over 512 threads (5 iters)
    float4* l4 = (float4*)lds;
    for (int s = threadIdx.x; s < (NI*NI)/2; s += 512) l4[s] = coefs4[s];
    __syncthreads();

    const int stride = gridDim.x * 512;
    for (int b = blockIdx.x*512 + threadIdx.x; b < NB; b += stride) {
        const float4 uu = u2[b];            // (x0,y0,x1,y1) — two points
        const float4 v0 = eval_pt(lds, uu.x, uu.y);
        const float4 v1 = eval_pt(lds, uu.z, uu.w);
        out[2*b]   = v0;
        out[2*b+1] = v1;
    }
}

extern "C" void kernel_launch(void* const* d_in, const int* in_sizes, int n_in,
                              void* d_out, int out_size, void* d_ws, size_t ws_size,
                              hipStream_t stream)
{
    const float* u    = (const float*)d_in[0];   // (B,2)
    const float* data = (const float*)d_in[1];   // (4,64,64)
    const int B  = in_sizes[0] / 2;              // 2,000,000
    const int NB = B / 2;                        // point pairs (B is even)

    float4* coefsQ = (float4*)d_ws;              // 34,848 B fp16 table

    solve_fused<<<1, 256, 0, stream>>>(data, coefsQ);
    interp<<<1024, 512, 0, stream>>>((const float4*)u, (const float4*)coefsQ,
                                     (float4*)d_out, NB);
}

// Round 2
// 87.123 us; speedup vs baseline: 1.0301x; 1.0039x over previous
//
#include <hip/hip_runtime.h>
#include <math.h>

#define MX 64
#define NC 4
#define NI 66          // MX + 2
#define NINT 62        // interior tridiagonal unknowns (c2..c63)

typedef _Float16 half4  __attribute__((ext_vector_type(4)));
typedef _Float16 half2v __attribute__((ext_vector_type(2)));

// ---------------------------------------------------------------------------
// Compile-time Thomas constants for the (1/6, 2/3, 1/6) tridiagonal system.
// ---------------------------------------------------------------------------
struct TC { float m[NINT]; float inv[NINT]; };
constexpr TC make_tc() {
    TC tc{};
    double dp = 2.0/3.0;
    tc.m[0] = 0.0f;
    tc.inv[0] = (float)(1.0/dp);
    for (int j = 1; j < NINT; ++j) {
        double m = (1.0/6.0) / dp;
        tc.m[j] = (float)m;
        dp = 2.0/3.0 - m*(1.0/6.0);
        tc.inv[j] = (float)(1.0/dp);
    }
    return tc;
}
__constant__ constexpr TC g_tc = make_tc();

// ---------------------------------------------------------------------------
// Interpolation inner: packed-fp16 basis (both axes in one Horner chain),
// 16 LDS half4 gathers, 40 pk_fma dot ops.
// ---------------------------------------------------------------------------
__device__ __forceinline__ float4 eval_pt(const half4* __restrict__ lds,
                                          float ux, float uy)
{
    const float unx = ux * 63.0f;
    const float uny = uy * 63.0f;

    // i = min(trunc(un), 62); t = un - i   (== reference _axis_index for u in [0,1])
    int ix = (int)unx; ix = ix > 62 ? 62 : ix;
    int iy = (int)uny; iy = iy > 62 ? 62 : iy;
    const float tx = unx - (float)ix;
    const float ty = uny - (float)iy;

    // packed (tx,ty) basis, coefficients pre-divided by 6:
    // b0 = ((-1/6 t + 1/2) t - 1/2) t + 1/6
    // b1 = (( 1/2 t - 1  ) t      ) t + 2/3
    // b2 = ((-1/2 t + 1/2) t + 1/2) t + 1/6
    // b3 = 1/6 t^3
    const half2v t = __builtin_bit_cast(half2v, __builtin_amdgcn_cvt_pkrtz(tx, ty));
    const half2v c16  = half2v{(_Float16)(1.0f/6.0f), (_Float16)(1.0f/6.0f)};
    const half2v ch   = half2v{(_Float16)0.5f,  (_Float16)0.5f};
    const half2v cnh  = half2v{(_Float16)-0.5f, (_Float16)-0.5f};
    const half2v cn16 = half2v{(_Float16)(-1.0f/6.0f), (_Float16)(-1.0f/6.0f)};
    const half2v cn1  = half2v{(_Float16)-1.0f, (_Float16)-1.0f};
    const half2v c23  = half2v{(_Float16)(2.0f/3.0f), (_Float16)(2.0f/3.0f)};

    const half2v t2 = t*t;
    half2v b0 = (cn16*t + ch)*t;  b0 = (b0 + cnh)*t + c16;   // (bx0, by0)
    half2v b1 = (ch*t + cn1)*t2 + c23;                        // (bx1, by1)
    half2v b2 = (cnh*t + ch)*t;   b2 = (b2 + ch)*t + c16;     // (bx2, by2)
    half2v b3 = c16*(t*t2);                                   // (bx3, by3)

    // broadcast halves (op_sel-foldable)
    const half2v by0 = __builtin_shufflevector(b0, b0, 1, 1);
    const half2v by1 = __builtin_shufflevector(b1, b1, 1, 1);
    const half2v by2 = __builtin_shufflevector(b2, b2, 1, 1);
    const half2v by3 = __builtin_shufflevector(b3, b3, 1, 1);
    const half2v bx[4] = {
        __builtin_shufflevector(b0, b0, 0, 0),
        __builtin_shufflevector(b1, b1, 0, 0),
        __builtin_shufflevector(b2, b2, 0, 0),
        __builtin_shufflevector(b3, b3, 0, 0),
    };

    const half4* r = lds + (ix*NI + iy);
    half2v t01, t23;
    #pragma unroll
    for (int ar = 0; ar < 4; ++ar) {
        const half4 c0 = r[ar*NI + 0];
        const half4 c1 = r[ar*NI + 1];
        const half4 c2 = r[ar*NI + 2];
        const half4 c3 = r[ar*NI + 3];
        half2v a01 = c0.lo*by0 + c1.lo*by1 + c2.lo*by2 + c3.lo*by3;
        half2v a23 = c0.hi*by0 + c1.hi*by1 + c2.hi*by2 + c3.hi*by3;
        if (ar == 0) { t01 = a01*bx[0];        t23 = a23*bx[0]; }
        else         { t01 = a01*bx[ar] + t01; t23 = a23*bx[ar] + t23; }
    }
    return make_float4((float)t01.x, (float)t01.y, (float)t23.x, (float)t23.y);
}

// ---------------------------------------------------------------------------
// R6: SINGLE fused kernel. Every block redundantly solves the 4x(64x64)
// separable B-spline system into its own LDS table (deterministic fp32 ops ->
// bit-identical fp16 table in every block -> output identical to the 2-kernel
// version). This removes: the solve dispatch, the 34.8 KB global round-trip,
// the interp preload loop, and one graph-node launch overhead. The solve is
// ~2 us of serial-chain latency and runs CONCURRENTLY in all 512 blocks.
//
// LDS: 34,848 B fp16 table + 34,320 B fp32 transpose scratch (2 channels at
// a time, reused across 2 chunks) = 69,168 B -> 2 blocks/CU, 512 blocks = all
// resident. __launch_bounds__(512,4) caps VGPR at 128 so residency holds
// (solve keeps w[62] live ~75 regs).
// ---------------------------------------------------------------------------
__global__ __launch_bounds__(512, 4) void fused(const float4* __restrict__ u2,
                                                const float*  __restrict__ data,
                                                float4* __restrict__ out, int NB)
{
    __shared__ half4 chS[NI*NI];        // 34,848 B fp16 coefficient table
    __shared__ float cxS[2][NI][65];    // 34,320 B x-pass scratch (2 channels)
    const int t = threadIdx.x;
    const float a = 1.0f/6.0f;

    #pragma unroll
    for (int c2 = 0; c2 < 2; ++c2) {
        // ---- Phase A: x-pass for channels {2*c2, 2*c2+1}: 128 lines ----
        if (t < 128) {
            const int cl = t >> 6, y = t & 63;
            const int c  = c2*2 + cl;
            const float* g = data + c*(MX*MX) + y;
            float w[NINT];
            const float d0 = g[0];
            #pragma unroll
            for (int j = 0; j < NINT; ++j) w[j] = g[(j+1)*MX];   // prefetch all
            const float dM = g[63*MX];
            w[0]      -= a*d0;
            w[NINT-1] -= a*dM;
            #pragma unroll
            for (int j = 1; j < NINT; ++j) w[j] -= g_tc.m[j]*w[j-1];
            float x = w[NINT-1] * g_tc.inv[NINT-1];
            const float c63 = x;
            cxS[cl][63][y] = x;
            #pragma unroll
            for (int j = NINT-2; j >= 0; --j) {
                x = (w[j] - a*x) * g_tc.inv[j];
                cxS[cl][j+2][y] = x;
            }
            cxS[cl][0][y]  = 2.0f*d0 - x;
            cxS[cl][1][y]  = d0;
            cxS[cl][64][y] = dM;
            cxS[cl][65][y] = 2.0f*dM - c63;
        }
        __syncthreads();

        // ---- Phase B: y-pass, 132 lines; results -> fp16 table ----
        if (t < 2*NI) {
            const int cl = t / NI;
            const int i  = t - cl*NI;
            const int c  = c2*2 + cl;
            const float* g = &cxS[cl][i][0];
            _Float16* o = ((_Float16*)&chS[i*NI]) + c;

            float w[NINT];
            const float d0 = g[0];
            #pragma unroll
            for (int j = 0; j < NINT; ++j) w[j] = g[j+1];
            const float dM = g[63];
            w[0]      -= a*d0;
            w[NINT-1] -= a*dM;
            #pragma unroll
            for (int j = 1; j < NINT; ++j) w[j] -= g_tc.m[j]*w[j-1];
            float x = w[NINT-1] * g_tc.inv[NINT-1];
            const float c63 = x;
            o[63*NC] = (_Float16)x;
            #pragma unroll
            for (int j = NINT-2; j >= 0; --j) {
                x = (w[j] - a*x) * g_tc.inv[j];
                o[(j+2)*NC] = (_Float16)x;
            }
            o[0*NC]  = (_Float16)(2.0f*d0 - x);
            o[1*NC]  = (_Float16)d0;
            o[64*NC] = (_Float16)dM;
            o[65*NC] = (_Float16)(2.0f*dM - c63);
        }
        __syncthreads();   // also protects cxS reuse by next chunk
    }

    // ---- Interpolation main loop: grid-stride over point pairs ----
    const int stride = gridDim.x * 512;
    for (int b = blockIdx.x*512 + t; b < NB; b += stride) {
        const float4 uu = u2[b];            // (x0,y0,x1,y1) — two points
        const float4 v0 = eval_pt(chS, uu.x, uu.y);
        const float4 v1 = eval_pt(chS, uu.z, uu.w);
        out[2*b]   = v0;
        out[2*b+1] = v1;
    }
}

extern "C" void kernel_launch(void* const* d_in, const int* in_sizes, int n_in,
                              void* d_out, int out_size, void* d_ws, size_t ws_size,
                              hipStream_t stream)
{
    const float* u    = (const float*)d_in[0];   // (B,2)
    const float* data = (const float*)d_in[1];   // (4,64,64)
    const int B  = in_sizes[0] / 2;              // 2,000,000
    const int NB = B / 2;                        // point pairs (B is even)

    // 512 blocks = exactly 2 resident blocks/CU on 256 CUs (LDS-limited),
    // so every block's in-LDS solve is paid once, concurrently.
    fused<<<512, 512, 0, stream>>>((const float4*)u, data, (float4*)d_out, NB);
}

// Round 3
// 82.959 us; speedup vs baseline: 1.0818x; 1.0502x over previous
//
#include <hip/hip_runtime.h>
#include <math.h>

#define MX 64
#define NC 4
#define NI 66          // MX + 2
#define NINT 62        // interior tridiagonal unknowns (c2..c63)

typedef _Float16 half4  __attribute__((ext_vector_type(4)));
typedef _Float16 half8  __attribute__((ext_vector_type(8)));
typedef _Float16 half2v __attribute__((ext_vector_type(2)));

// ---------------------------------------------------------------------------
// Compile-time Thomas constants for the (1/6, 2/3, 1/6) tridiagonal system.
// ---------------------------------------------------------------------------
struct TC { float m[NINT]; float inv[NINT]; };
constexpr TC make_tc() {
    TC tc{};
    double dp = 2.0/3.0;
    tc.m[0] = 0.0f;
    tc.inv[0] = (float)(1.0/dp);
    for (int j = 1; j < NINT; ++j) {
        double m = (1.0/6.0) / dp;
        tc.m[j] = (float)m;
        dp = 2.0/3.0 - m*(1.0/6.0);
        tc.inv[j] = (float)(1.0/dp);
    }
    return tc;
}
__constant__ constexpr TC g_tc = make_tc();

// ---------------------------------------------------------------------------
// R7: dual-parity pair tables -> all gathers are aligned ds_read_b128.
//
// TA (== chS, unchanged layout): 66 x-rows of 66 half4 entries (528 B/row);
//   16 B pair k covers y = {2k, 2k+1}, k in [0,33).
// TB (built after solve, overlaying the dead fp32 scratch): 66 x-rows of
//   32 pairs (512 B/row); pair k covers y = {2k+1, 2k+2}.
// A 4-entry row fetch y0..y0+3 is two aligned b128 from TA (y0 even) or TB
// (y0 odd). 8 wide gathers/pt instead of 16 narrow ones; identical FMA math.
// ---------------------------------------------------------------------------
__device__ __forceinline__ float4 eval_pt(const char* __restrict__ taB,
                                          const char* __restrict__ tbB,
                                          float ux, float uy)
{
    const float unx = ux * 63.0f;
    const float uny = uy * 63.0f;

    // i = min(trunc(un), 62); t = un - i   (== reference _axis_index for u in [0,1])
    int ix = (int)unx; ix = ix > 62 ? 62 : ix;
    int iy = (int)uny; iy = iy > 62 ? 62 : iy;
    const float tx = unx - (float)ix;
    const float ty = uny - (float)iy;

    // packed (tx,ty) basis, coefficients pre-divided by 6:
    // b0 = ((-1/6 t + 1/2) t - 1/2) t + 1/6
    // b1 = (( 1/2 t - 1  ) t      ) t + 2/3
    // b2 = ((-1/2 t + 1/2) t + 1/2) t + 1/6
    // b3 = 1/6 t^3
    const half2v t = __builtin_bit_cast(half2v, __builtin_amdgcn_cvt_pkrtz(tx, ty));
    const half2v c16  = half2v{(_Float16)(1.0f/6.0f), (_Float16)(1.0f/6.0f)};
    const half2v ch   = half2v{(_Float16)0.5f,  (_Float16)0.5f};
    const half2v cnh  = half2v{(_Float16)-0.5f, (_Float16)-0.5f};
    const half2v cn16 = half2v{(_Float16)(-1.0f/6.0f), (_Float16)(-1.0f/6.0f)};
    const half2v cn1  = half2v{(_Float16)-1.0f, (_Float16)-1.0f};
    const half2v c23  = half2v{(_Float16)(2.0f/3.0f), (_Float16)(2.0f/3.0f)};

    const half2v t2 = t*t;
    half2v b0 = (cn16*t + ch)*t;  b0 = (b0 + cnh)*t + c16;   // (bx0, by0)
    half2v b1 = (ch*t + cn1)*t2 + c23;                        // (bx1, by1)
    half2v b2 = (cnh*t + ch)*t;   b2 = (b2 + ch)*t + c16;     // (bx2, by2)
    half2v b3 = c16*(t*t2);                                   // (bx3, by3)

    // broadcast halves (op_sel-foldable)
    const half2v by0 = __builtin_shufflevector(b0, b0, 1, 1);
    const half2v by1 = __builtin_shufflevector(b1, b1, 1, 1);
    const half2v by2 = __builtin_shufflevector(b2, b2, 1, 1);
    const half2v by3 = __builtin_shufflevector(b3, b3, 1, 1);
    const half2v bx[4] = {
        __builtin_shufflevector(b0, b0, 0, 0),
        __builtin_shufflevector(b1, b1, 0, 0),
        __builtin_shufflevector(b2, b2, 0, 0),
        __builtin_shufflevector(b3, b3, 0, 0),
    };

    // parity-selected table: even iy -> TA pair iy/2; odd iy -> TB pair (iy-1)/2
    const int odd = iy & 1;
    const int ke  = iy >> 1;
    const char* base    = odd ? tbB : taB;
    const int   rstride = odd ? 512 : 528;           // bytes per x-row
    const char* rp = base + ix*rstride + ke*16;

    half2v t01, t23;
    #pragma unroll
    for (int ar = 0; ar < 4; ++ar) {
        const half8 p0 = *(const half8*)(rp);        // entries y0, y0+1 (4ch each)
        const half8 p1 = *(const half8*)(rp + 16);   // entries y0+2, y0+3
        rp += rstride;
        const half2v e0c01 = __builtin_shufflevector(p0, p0, 0, 1);
        const half2v e0c23 = __builtin_shufflevector(p0, p0, 2, 3);
        const half2v e1c01 = __builtin_shufflevector(p0, p0, 4, 5);
        const half2v e1c23 = __builtin_shufflevector(p0, p0, 6, 7);
        const half2v e2c01 = __builtin_shufflevector(p1, p1, 0, 1);
        const half2v e2c23 = __builtin_shufflevector(p1, p1, 2, 3);
        const half2v e3c01 = __builtin_shufflevector(p1, p1, 4, 5);
        const half2v e3c23 = __builtin_shufflevector(p1, p1, 6, 7);
        half2v a01 = e0c01*by0 + e1c01*by1 + e2c01*by2 + e3c01*by3;
        half2v a23 = e0c23*by0 + e1c23*by1 + e2c23*by2 + e3c23*by3;
        if (ar == 0) { t01 = a01*bx[0];        t23 = a23*bx[0]; }
        else         { t01 = a01*bx[ar] + t01; t23 = a23*bx[ar] + t23; }
    }
    return make_float4((float)t01.x, (float)t01.y, (float)t23.x, (float)t23.y);
}

// ---------------------------------------------------------------------------
// Single fused kernel. Every block redundantly solves the 4x(64x64) system
// into LDS (deterministic -> bit-identical in every block). The fp32 x-pass
// scratch is overlaid by TB after the solve (scratch dead after phase B):
// LDS = TA 34,848 + union(scratch 34,320, TB 33,792) = 69,168 B -> 2 blk/CU.
// ---------------------------------------------------------------------------
__global__ __launch_bounds__(512, 4) void fused(const float2* __restrict__ uv,
                                                const float*  __restrict__ data,
                                                float4* __restrict__ out, int B)
{
    __shared__ __align__(16) half4 chS[NI*NI];      // TA: 34,848 B
    __shared__ __align__(16) char  arenaB[2*NI*65*4]; // scratch / TB union: 34,320 B
    float (*cxS)[NI][65] = (float(*)[NI][65])arenaB;
    const int t = threadIdx.x;
    const float a = 1.0f/6.0f;

    #pragma unroll
    for (int c2 = 0; c2 < 2; ++c2) {
        // ---- Phase A: x-pass for channels {2*c2, 2*c2+1}: 128 lines ----
        if (t < 128) {
            const int cl = t >> 6, y = t & 63;
            const int c  = c2*2 + cl;
            const float* g = data + c*(MX*MX) + y;
            float w[NINT];
            const float d0 = g[0];
            #pragma unroll
            for (int j = 0; j < NINT; ++j) w[j] = g[(j+1)*MX];   // prefetch all
            const float dM = g[63*MX];
            w[0]      -= a*d0;
            w[NINT-1] -= a*dM;
            #pragma unroll
            for (int j = 1; j < NINT; ++j) w[j] -= g_tc.m[j]*w[j-1];
            float x = w[NINT-1] * g_tc.inv[NINT-1];
            const float c63 = x;
            cxS[cl][63][y] = x;
            #pragma unroll
            for (int j = NINT-2; j >= 0; --j) {
                x = (w[j] - a*x) * g_tc.inv[j];
                cxS[cl][j+2][y] = x;
            }
            cxS[cl][0][y]  = 2.0f*d0 - x;
            cxS[cl][1][y]  = d0;
            cxS[cl][64][y] = dM;
            cxS[cl][65][y] = 2.0f*dM - c63;
        }
        __syncthreads();

        // ---- Phase B: y-pass, 132 lines; results -> fp16 table (TA) ----
        if (t < 2*NI) {
            const int cl = t / NI;
            const int i  = t - cl*NI;
            const int c  = c2*2 + cl;
            const float* g = &cxS[cl][i][0];
            _Float16* o = ((_Float16*)&chS[i*NI]) + c;

            float w[NINT];
            const float d0 = g[0];
            #pragma unroll
            for (int j = 0; j < NINT; ++j) w[j] = g[j+1];
            const float dM = g[63];
            w[0]      -= a*d0;
            w[NINT-1] -= a*dM;
            #pragma unroll
            for (int j = 1; j < NINT; ++j) w[j] -= g_tc.m[j]*w[j-1];
            float x = w[NINT-1] * g_tc.inv[NINT-1];
            const float c63 = x;
            o[63*NC] = (_Float16)x;
            #pragma unroll
            for (int j = NINT-2; j >= 0; --j) {
                x = (w[j] - a*x) * g_tc.inv[j];
                o[(j+2)*NC] = (_Float16)x;
            }
            o[0*NC]  = (_Float16)(2.0f*d0 - x);
            o[1*NC]  = (_Float16)d0;
            o[64*NC] = (_Float16)dM;
            o[65*NC] = (_Float16)(2.0f*dM - c63);
        }
        __syncthreads();   // also protects cxS reuse by next chunk
    }

    // ---- Build TB (shifted pair table) over the dead scratch ----
    // TB[i][k] = entries (y=2k+1, y=2k+2), k in [0,32): copy from TA.
    {
        half4* TB4 = (half4*)arenaB;
        for (int s = t; s < NI*32; s += 512) {
            const int i = s >> 5, k = s & 31;
            const half4* src = chS + i*NI + 2*k + 1;
            TB4[(i*32 + k)*2 + 0] = src[0];
            TB4[(i*32 + k)*2 + 1] = src[1];
        }
    }
    __syncthreads();

    // ---- Interpolation main loop: one point per thread, dense streams ----
    const char* taB = (const char*)chS;
    const char* tbB = (const char*)arenaB;
    const int stride = gridDim.x * 512;
    for (int b = blockIdx.x*512 + t; b < B; b += stride) {
        const float2 uu = uv[b];
        out[b] = eval_pt(taB, tbB, uu.x, uu.y);
    }
}

extern "C" void kernel_launch(void* const* d_in, const int* in_sizes, int n_in,
                              void* d_out, int out_size, void* d_ws, size_t ws_size,
                              hipStream_t stream)
{
    const float* u    = (const float*)d_in[0];   // (B,2)
    const float* data = (const float*)d_in[1];   // (4,64,64)
    const int B  = in_sizes[0] / 2;              // 2,000,000

    // 512 blocks = exactly 2 resident blocks/CU (LDS-limited), so every
    // block's in-LDS solve is paid once, concurrently.
    fused<<<512, 512, 0, stream>>>((const float2*)u, data, (float4*)d_out, B);
}